// Round 6
// baseline (10149.039 us; speedup 1.0000x reference)
//
#include <hip/hip_runtime.h>

#define L_SEQ 128
#define BATCH 512
#define DIM   512

typedef __attribute__((ext_vector_type(8))) short bf16x8;
typedef __attribute__((ext_vector_type(4))) float f32x4;
typedef unsigned short ushort_t;

#define MFMA16(a,b,c) __builtin_amdgcn_mfma_f32_16x16x32_bf16((a),(b),(c),0,0,0)

__device__ __forceinline__ ushort_t f2bf(float f) {
  union { float f; unsigned u; } v; v.f = f;
  unsigned u = v.u;
  unsigned r = (u + 0x7FFFu + ((u >> 16) & 1u)) >> 16;  // RNE
  return (ushort_t)r;
}
__device__ __forceinline__ float bf2f(ushort_t b) {
  union { unsigned u; float f; } v; v.u = ((unsigned)b) << 16;
  return v.f;
}
// byte offset into a [16][512] bf16 image, row stride 1024B, XOR-swizzled 16B chunks
__device__ __forceinline__ int aoff(int r, int k) {
  return (r << 10) + ((((k >> 3) ^ (r & 7)) << 4) | ((k & 7) << 1));
}
__device__ __forceinline__ float tanh_f(float x) {
  x = fminf(fmaxf(x, -15.f), 15.f);
  float e = __expf(2.f * x);
  return (e - 1.f) / (e + 1.f);
}
__device__ __forceinline__ float sigm_f(float x) {
  x = fminf(fmaxf(x, -30.f), 30.f);
  return 1.f / (1.f + __expf(-x));
}
__device__ __forceinline__ void barrier_nd() {
  asm volatile("s_waitcnt lgkmcnt(0)" ::: "memory");
  __builtin_amdgcn_s_barrier();
}

// ============================================================================
// Weight layout (per matrix 512x512 bf16 = 262144 ushorts), N-split aware:
//   idx = m*262144 + hf*131072 + s*8192 + w*1024 + g*256 + cc*8 + j
//   where c = hf*256 + w*32 + cc (out col), k = s*32 + g*8 + j.
//   => per (hf, slice s, wave w): 1024 ushorts (2KB) contiguous.
// m: 0:W1 1:W2 2:Whr 3:Whz 4:Whn 5:Wir 6:Wiz 7:Win
// ws map (ushorts): [0] weights 2097152 | [2097152] gib (bf16 gi[L][B][1536])
// flags: 4KB carved inside Wir image (byte 2621440) — Wir only used by gi_gemm,
// which runs BEFORE the flag memset.  xbuf: d_out reused as scratch.
// ============================================================================

__global__ __launch_bounds__(256) void prep_w(const float* __restrict__ W1,
                                              const float* __restrict__ W2,
                                              const float* __restrict__ Whh,
                                              const float* __restrict__ Wih,
                                              ushort_t* __restrict__ wsb) {
  unsigned idx = blockIdx.x * 256u + threadIdx.x;   // 0 .. 2097151
  unsigned m  = idx >> 18;
  unsigned r  = idx & 262143u;
  unsigned hf = r >> 17;  r &= 131071u;
  unsigned s  = r >> 13;
  unsigned r1 = r & 8191u;
  unsigned w  = r1 >> 10;
  unsigned r2 = r1 & 1023u;
  unsigned g  = r2 >> 8;
  unsigned r3 = r2 & 255u;
  unsigned cc = r3 >> 3;
  unsigned j  = r3 & 7u;
  unsigned c  = hf * 256u + w * 32u + cc;
  unsigned k  = s * 32u + g * 8u + j;
  float v;
  if (m == 0)      v = W1[c * 512u + k];
  else if (m == 1) v = W2[c * 512u + k];
  else if (m < 5)  v = Whh[((m - 2u) * 512u + c) * 512u + k];
  else             v = Wih[((m - 5u) * 512u + c) * 512u + k];
  wsb[idx] = f2bf(v);
}

// ---- precompute gi[i][b][0:1536] = emb[x[b,i]] @ W_ih^T + b_ih  (bf16, nt stores) ----
__global__ __launch_bounds__(256) void gi_gemm(const float* __restrict__ emb,
                                               const int* __restrict__ x,
                                               const float* __restrict__ bih,
                                               const ushort_t* __restrict__ wsb,
                                               ushort_t* __restrict__ gib) {
  __shared__ __align__(16) unsigned char As[64 * 1024];
  const int tid = threadIdx.x;
  const int mb = blockIdx.x;            // 0..1023
  const int nb = blockIdx.y;            // 0..5
  const int i = (mb * 64) >> 9;
  const int brow0 = (mb * 64) & 511;
  {
    int r = tid >> 2;
    int xv = x[(brow0 + r) * L_SEQ + i];
    const float4* er4 = (const float4*)(emb + (size_t)xv * DIM);
#pragma unroll
    for (int cc = 0; cc < 16; ++cc) {
      int c = (tid & 3) * 16 + cc;
      float4 fa = er4[c * 2], fb = er4[c * 2 + 1];
      union { ushort_t u[8]; bf16x8 v; } pk;
      pk.u[0] = f2bf(fa.x); pk.u[1] = f2bf(fa.y); pk.u[2] = f2bf(fa.z); pk.u[3] = f2bf(fa.w);
      pk.u[4] = f2bf(fb.x); pk.u[5] = f2bf(fb.y); pk.u[6] = f2bf(fb.z); pk.u[7] = f2bf(fb.w);
      *(bf16x8*)(As + aoff(r, c * 8)) = pk.v;
    }
  }
  __syncthreads();
  const int wave = tid >> 6, lane = tid & 63;
  const int lr = lane & 15, lg = lane >> 4;
  const int ncol0 = nb * 256 + wave * 64;
  const int gate = nb >> 1;
  const ushort_t* wimg = wsb + (5u + (unsigned)gate) * 262144u;
  int bofs[4];
#pragma unroll
  for (int nf = 0; nf < 4; ++nf) {
    int cg = (nb & 1) * 256 + wave * 64 + nf * 16 + lr;  // gate-local col
    int hfc = cg >> 8, chw = cg & 255;
    bofs[nf] = hfc * 131072 + (chw >> 5) * 1024 + (chw & 31) * 8 + lg * 256;
  }
  f32x4 acc[4][4];
  f32x4 z = {0.f, 0.f, 0.f, 0.f};
#pragma unroll
  for (int mf = 0; mf < 4; ++mf)
#pragma unroll
    for (int nf = 0; nf < 4; ++nf) acc[mf][nf] = z;
#pragma unroll
  for (int kf = 0; kf < 16; ++kf) {
    bf16x8 a[4];
#pragma unroll
    for (int mf = 0; mf < 4; ++mf)
      a[mf] = *(const bf16x8*)(As + aoff((mf << 4) + lr, (kf << 5) + (lg << 3)));
#pragma unroll
    for (int nf = 0; nf < 4; ++nf) {
      bf16x8 b = *(const bf16x8*)(wimg + kf * 8192 + bofs[nf]);
#pragma unroll
      for (int mf = 0; mf < 4; ++mf) acc[mf][nf] = MFMA16(a[mf], b, acc[mf][nf]);
    }
  }
#pragma unroll
  for (int nf = 0; nf < 4; ++nf) {
    int col = ncol0 + (nf << 4) + lr;
    float bb = bih[col];
#pragma unroll
    for (int mf = 0; mf < 4; ++mf)
#pragma unroll
      for (int j = 0; j < 4; ++j) {
        int row = (mf << 4) + (lg << 2) + j;
        __builtin_nontemporal_store(f2bf(acc[mf][nf][j] + bb),
            gib + (size_t)(i * BATCH + brow0 + row) * 1536 + col);
      }
  }
}

// ============================================================================
// scan: 64 WGs x 512 thr.  WG (g,hf): batch rows g*16..+16, cols hf*256..+255.
// Weights direct L2->VGPR (asm ring, counted vmcnt).  Half-image exchange via
// u64 LLC atomics in d_out scratch; epoch flags; own-half-K first.
// ============================================================================

#define ISSUE16(BASE) do { \
    _Pragma("unroll") \
    for (int q_ = 0; q_ < 16; ++q_) { \
      int s_ = (q_ < 8) ? (sb0 + q_) : (sb1 + q_ - 8); \
      const ushort_t* a_ = (BASE) + (unsigned)s_ * 8192u; \
      asm volatile("global_load_dwordx4 %0, %2, off\n\t" \
                   "global_load_dwordx4 %1, %2, off offset:256" \
                   : "=&v"(Rr[q_][0]), "=&v"(Rr[q_][1]) : "v"(a_) : "memory"); \
    } } while (0)

#define CONS1(IMG, Q, SS, VM) do { \
    asm volatile("s_waitcnt vmcnt(" #VM ")" ::: "memory"); \
    __builtin_amdgcn_sched_barrier(0); \
    bf16x8 a_ = *(const bf16x8*)((IMG) + (lr << 10) + ((((SS) * 4 + lg) ^ (lr & 7)) << 4)); \
    acc[0] = MFMA16(a_, Rr[Q][0], acc[0]); \
    acc[1] = MFMA16(a_, Rr[Q][1], acc[1]); } while (0)

#define CONS_LO(IMG) do { CONS1(IMG,0,sb0+0,30); CONS1(IMG,1,sb0+1,28); \
    CONS1(IMG,2,sb0+2,26); CONS1(IMG,3,sb0+3,24); CONS1(IMG,4,sb0+4,22); \
    CONS1(IMG,5,sb0+5,20); CONS1(IMG,6,sb0+6,18); CONS1(IMG,7,sb0+7,16); } while (0)
#define CONS_HI(IMG) do { CONS1(IMG,8,sb1+0,14); CONS1(IMG,9,sb1+1,12); \
    CONS1(IMG,10,sb1+2,10); CONS1(IMG,11,sb1+3,8); CONS1(IMG,12,sb1+4,6); \
    CONS1(IMG,13,sb1+5,4); CONS1(IMG,14,sb1+6,2); CONS1(IMG,15,sb1+7,0); } while (0)

#define HEAD() do { \
    asm volatile("" :: "v"(o0), "v"(o1)); \
    asm volatile("s_waitcnt vmcnt(0)" ::: "memory"); \
    __syncthreads(); \
    if (tid == 0) (void)__hip_atomic_fetch_add(myflag, 1u, __ATOMIC_RELAXED, __HIP_MEMORY_SCOPE_AGENT); \
  } while (0)

#define EXPORT(IMG) do { \
    int row_ = tid >> 5, ch_ = tid & 31; \
    union { unsigned long long u[2]; bf16x8 v; } pk_; \
    pk_.v = *(const bf16x8*)((IMG) + (row_ << 10) + (((hf * 32 + ch_) ^ (row_ & 7)) << 4)); \
    unsigned long long* d_ = xb + ((size_t)((g * 2 + (int)(pc & 1u)) * 2 + hf) * 1024) + tid * 2; \
    o0 = __hip_atomic_exchange(d_,     pk_.u[0], __ATOMIC_RELAXED, __HIP_MEMORY_SCOPE_AGENT); \
    o1 = __hip_atomic_exchange(d_ + 1, pk_.u[1], __ATOMIC_RELAXED, __HIP_MEMORY_SCOPE_AGENT); \
  } while (0)

#define IMPORT(IMG) do { \
    if (tid == 0) { unsigned tgt_ = pc + 1u; \
      while (__hip_atomic_load(pflag, __ATOMIC_RELAXED, __HIP_MEMORY_SCOPE_AGENT) < tgt_) \
        __builtin_amdgcn_s_sleep(2); } \
    __builtin_amdgcn_s_barrier(); \
    int row_ = tid >> 5, ch_ = tid & 31; \
    unsigned long long* s_ = xb + ((size_t)((g * 2 + (int)(pc & 1u)) * 2 + (hf ^ 1)) * 1024) + tid * 2; \
    union { unsigned long long u[2]; bf16x8 v; } pk_; \
    pk_.u[0] = __hip_atomic_fetch_add(s_,     0ull, __ATOMIC_RELAXED, __HIP_MEMORY_SCOPE_AGENT); \
    pk_.u[1] = __hip_atomic_fetch_add(s_ + 1, 0ull, __ATOMIC_RELAXED, __HIP_MEMORY_SCOPE_AGENT); \
    *(bf16x8*)((IMG) + (row_ << 10) + (((((hf ^ 1) * 32) + ch_) ^ (row_ & 7)) << 4)) = pk_.v; \
    barrier_nd(); \
  } while (0)

__global__ __launch_bounds__(512, 2) void scan_kernel(
    const float* __restrict__ t, const int* __restrict__ x,
    const ushort_t* __restrict__ wsb,
    const float* __restrict__ b1g, const float* __restrict__ b2g,
    const float* __restrict__ bhhg,
    const ushort_t* __restrict__ gib,
    unsigned* __restrict__ flags,
    float* __restrict__ out) {
  __shared__ __align__(16) unsigned char S0[16 * 1024];
  __shared__ __align__(16) unsigned char S1[16 * 1024];
  __shared__ float b1s[512], b2s[512], bhhs[1536];

  const int tid = threadIdx.x;
  const int wave = tid >> 6, lane = tid & 63;
  const int lr = lane & 15, lg = lane >> 4;
  const int g = blockIdx.x >> 1, hf = blockIdx.x & 1;
  const int b0 = g * 16;
  const int colbase = hf * 256 + wave * 32;
  const int sb0 = hf * 8, sb1 = (hf ^ 1) * 8;
  unsigned* myflag = flags + (g * 2 + hf) * 16;
  unsigned* pflag  = flags + (g * 2 + (hf ^ 1)) * 16;
  unsigned long long* xb = (unsigned long long*)out;

  const ushort_t* wl = wsb + (unsigned)hf * 131072u + (unsigned)wave * 1024u
                           + (unsigned)lg * 256u + (unsigned)lr * 8u;
  const ushort_t* base_w1 = wl;
  const ushort_t* base_w2 = wl + 262144u;
  const ushort_t* base_wr = wl + 2u * 262144u;
  const ushort_t* base_wz = wl + 3u * 262144u;
  const ushort_t* base_wn = wl + 4u * 262144u;

  { int q = tid; b1s[q] = b1g[q]; b2s[q] = b2g[q]; }
  for (int q = tid; q < 1536; q += 512) bhhs[q] = bhhg[q];
  __syncthreads();

  float h[2][4];
#pragma unroll
  for (int nf = 0; nf < 2; ++nf)
#pragma unroll
    for (int j = 0; j < 4; ++j) h[nf][j] = 0.f;

  float dtj[4], mj[4];
#pragma unroll
  for (int j = 0; j < 4; ++j) {
    int b = b0 + lg * 4 + j;
    mj[j] = (x[b * L_SEQ + 0] != 0) ? 1.f : 0.f;
    dtj[j] = 1e-6f;
  }

  unsigned pc = 0;
  unsigned long long o0 = 0, o1 = 0;
  bf16x8 Rr[16][2];
  f32x4 acc[2];
  const f32x4 z4 = {0.f, 0.f, 0.f, 0.f};

  for (int i = 0; i < L_SEQ; ++i) {
    if (i > 0) {
      float ksum[2][4] = {};
#pragma unroll 1
      for (int s4 = 0; s4 < 4; ++s4) {
        // ---- W1 @ eval-point image (S0) ----
        HEAD(); ISSUE16(base_w1); acc[0] = z4; acc[1] = z4;
        CONS_LO(S0); IMPORT(S0); CONS_HI(S0); ++pc;
#pragma unroll
        for (int nf = 0; nf < 2; ++nf) {
          int col = colbase + nf * 16 + lr; float bb = b1s[col];
#pragma unroll
          for (int j = 0; j < 4; ++j)
            *(ushort_t*)(S1 + aoff(lg * 4 + j, col)) = f2bf(tanh_f(acc[nf][j] + bb));
        }
        barrier_nd();
        EXPORT(S1);
        // ---- W2 @ u image (S1) ----
        HEAD(); ISSUE16(base_w2); acc[0] = z4; acc[1] = z4;
        CONS_LO(S1); IMPORT(S1); CONS_HI(S1); ++pc;
        const float wk = (s4 == 0 || s4 == 3) ? 1.f : 2.f;
        const float cs = (s4 < 2) ? 0.5f : 1.f;
#pragma unroll
        for (int nf = 0; nf < 2; ++nf) {
          int col = colbase + nf * 16 + lr; float bb = b2s[col];
#pragma unroll
          for (int j = 0; j < 4; ++j) {
            float kv = acc[nf][j] + bb;
            ksum[nf][j] += wk * kv;
            float nv;
            if (s4 < 3) {
              nv = h[nf][j] + cs * dtj[j] * kv;
            } else {
              float hev = h[nf][j] + dtj[j] * (1.f / 6.f) * ksum[nf][j];
              nv = (mj[j] > 0.5f) ? hev : h[nf][j];
              h[nf][j] = nv;                          // h_pre for GRU
            }
            *(ushort_t*)(S0 + aoff(lg * 4 + j, col)) = f2bf(nv);
          }
        }
        barrier_nd();
        EXPORT(S0);
      }
    }

    // gi loads for this step (latency hidden under gate phases)
    ushort_t gv[3][2][4];
#pragma unroll
    for (int nf = 0; nf < 2; ++nf)
#pragma unroll
      for (int j = 0; j < 4; ++j) {
        const ushort_t* gp = gib + (size_t)(i * BATCH + b0 + lg * 4 + j) * 1536
                                 + colbase + nf * 16 + lr;
        gv[0][nf][j] = __builtin_nontemporal_load(gp);
        gv[1][nf][j] = __builtin_nontemporal_load(gp + 512);
        gv[2][nf][j] = __builtin_nontemporal_load(gp + 1024);
      }
    float dtn[4], mn[4];
    if (i < L_SEQ - 1) {
#pragma unroll
      for (int j = 0; j < 4; ++j) {
        int b = b0 + lg * 4 + j;
        mn[j] = (x[b * L_SEQ + i + 1] != 0) ? 1.f : 0.f;
        dtn[j] = fmaxf(t[b * L_SEQ + i + 1] - t[b * L_SEQ + i], 1e-6f);
      }
    } else {
#pragma unroll
      for (int j = 0; j < 4; ++j) { mn[j] = mj[j]; dtn[j] = dtj[j]; }
    }

    f32x4 gh0[2], gh1[2], gh2[2];
    if (i > 0) {
      HEAD(); ISSUE16(base_wr); acc[0] = z4; acc[1] = z4;
      CONS_LO(S0); IMPORT(S0); CONS_HI(S0); ++pc;
      gh0[0] = acc[0]; gh0[1] = acc[1];
      ISSUE16(base_wz); acc[0] = z4; acc[1] = z4;
      CONS_LO(S0); CONS_HI(S0);
      gh1[0] = acc[0]; gh1[1] = acc[1];
      ISSUE16(base_wn); acc[0] = z4; acc[1] = z4;
      CONS_LO(S0); CONS_HI(S0);
      gh2[0] = acc[0]; gh2[1] = acc[1];
      barrier_nd();                                  // all S0 reads done before overwrite
    } else {
      gh0[0] = z4; gh0[1] = z4; gh1[0] = z4; gh1[1] = z4; gh2[0] = z4; gh2[1] = z4;
    }

    // GRU epilogue
#pragma unroll
    for (int nf = 0; nf < 2; ++nf) {
      int col = colbase + nf * 16 + lr;
      float br = bhhs[col], bz = bhhs[col + 512], bn = bhhs[col + 1024];
#pragma unroll
      for (int j = 0; j < 4; ++j) {
        float rr = sigm_f(bf2f(gv[0][nf][j]) + gh0[nf][j] + br);
        float zz = sigm_f(bf2f(gv[1][nf][j]) + gh1[nf][j] + bz);
        float nn = tanh_f(bf2f(gv[2][nf][j]) + rr * (gh2[nf][j] + bn));
        float hnew = (1.f - zz) * nn + zz * h[nf][j];
        float hv = (mj[j] > 0.5f) ? hnew : h[nf][j];
        h[nf][j] = hv;
        *(ushort_t*)(S0 + aoff(lg * 4 + j, col)) = f2bf(hv);
      }
    }
    barrier_nd();
    if (i < L_SEQ - 1) EXPORT(S0);
#pragma unroll
    for (int j = 0; j < 4; ++j) { dtj[j] = dtn[j]; mj[j] = mn[j]; }
  }

  // final handshake: partner must finish its last import before we overwrite xbuf(=out)
  asm volatile("" :: "v"(o0), "v"(o1));
  asm volatile("s_waitcnt vmcnt(0)" ::: "memory");
  __syncthreads();
  if (tid == 0) {
    (void)__hip_atomic_fetch_add(myflag, 1u, __ATOMIC_RELAXED, __HIP_MEMORY_SCOPE_AGENT);
    while (__hip_atomic_load(pflag, __ATOMIC_RELAXED, __HIP_MEMORY_SCOPE_AGENT) < 1144u)
      __builtin_amdgcn_s_sleep(2);
  }
  __builtin_amdgcn_s_barrier();
#pragma unroll
  for (int nf = 0; nf < 2; ++nf) {
    int col = colbase + nf * 16 + lr;
#pragma unroll
    for (int j = 0; j < 4; ++j) {
      int b = b0 + lg * 4 + j;
      out[(size_t)b * DIM + col] = h[nf][j];
    }
  }
}

extern "C" void kernel_launch(void* const* d_in, const int* in_sizes, int n_in,
                              void* d_out, int out_size, void* d_ws, size_t ws_size,
                              hipStream_t stream) {
  const float* t_   = (const float*)d_in[0];
  const float* emb  = (const float*)d_in[1];
  const float* Wih  = (const float*)d_in[2];
  const float* Whh  = (const float*)d_in[3];
  const float* bih  = (const float*)d_in[4];
  const float* bhh  = (const float*)d_in[5];
  const float* W1   = (const float*)d_in[6];
  const float* b1   = (const float*)d_in[7];
  const float* W2   = (const float*)d_in[8];
  const float* b2   = (const float*)d_in[9];
  const int*   x    = (const int*)d_in[10];
  float* out = (float*)d_out;
  (void)b2; (void)in_sizes; (void)n_in; (void)out_size; (void)ws_size;

  ushort_t* wsb = (ushort_t*)d_ws;                 // 2097152 ushorts of weight images
  ushort_t* gib = wsb + 2097152;                   // bf16 gi[L][B][1536]
  unsigned* flags = (unsigned*)((char*)d_ws + 2621440);  // inside Wir (gi_gemm-only region)

  hipLaunchKernelGGL(prep_w, dim3(8192), dim3(256), 0, stream, W1, W2, Whh, Wih, wsb);
  hipLaunchKernelGGL(gi_gemm, dim3(1024, 6), dim3(256), 0, stream, emb, x, bih, wsb, gib);
  hipMemsetAsync((void*)flags, 0, 4096, stream);   // after gi_gemm (flags overlay Wir)
  hipLaunchKernelGGL(scan_kernel, dim3(64), dim3(512), 0, stream,
                     t_, x, wsb, b1, b2, bhh, gib, flags, out);
}